// Round 13
// baseline (111.051 us; speedup 1.0000x reference)
//
#include <hip/hip_runtime.h>
#include <hip/hip_bf16.h>

// Problem constants: B=16, N=16384, D=256, grid 128x128, K=3 depthwise, GELU.
// coords = per-batch permutation of all cells -> collision-free, min=(0,0).
//
// R13 = R12 + software-pipelined column loads (depth 1). R12 counters
// (VALUBusy 15%, 3.9 TB/s eff, occ 21%) => latency-bound: column j's loads
// were consumed immediately. Now column j+1's loads issue BEFORE column j's
// compute, giving ~300+ cycles (plus 3 other waves) of cover per load.
#define BB 16
#define NN 16384
#define GW 128
#define TS 16
#define HS 18

typedef float f32x4 __attribute__((ext_vector_type(4)));

// ---------------------------------------------------------------------------
// Kernel 1: inverse permutation + zero-row init
// ---------------------------------------------------------------------------
__global__ __launch_bounds__(256) void build_inv_kernel(
    const int* __restrict__ coords, int* __restrict__ inv,
    float* __restrict__ zrow) {
  int i = blockIdx.x * blockDim.x + threadIdx.x;   // 0 .. B*N-1
  int b = i >> 14;
  int gx = coords[2 * (size_t)i];
  int gy = coords[2 * (size_t)i + 1];
  inv[(b << 14) + (gy << 7) + gx] = i & (NN - 1);
  if (blockIdx.x == 0) zrow[threadIdx.x] = 0.0f;   // 256 floats = 1 row
}

__device__ __forceinline__ float gelu_fast(float a) {
  // gelu_tanh(a) = a * sigmoid(1.5957691216*(a + 0.044715*a^3))
  // folded: sig = 1/(1+2^(-2.3022083*t))
  const float s = a * a;
  const float t = fmaf(0.044715f * a, s, a);
  const float e = __builtin_amdgcn_exp2f(t * -2.3022083f);
  return a * __builtin_amdgcn_rcpf(1.0f + e);
}

// load halo column j (6 stacked rows r0..r0+5) for this lane's 4 channels
#define LCOL(j, col)                                                      \
  _Pragma("unroll") for (int r6 = 0; r6 < 6; ++r6) {                      \
    const int n_ = __builtin_amdgcn_readfirstlane(s_inv[r0 + r6][j]);     \
    const float* p_ = (n_ >= 0) ? xb + ((size_t)n_ << 8) : zrow;          \
    col[r6] = *(const f32x4*)(p_ + c4);                                   \
  }

// ---------------------------------------------------------------------------
// Kernel 2: 16x16 tile; wave w -> rows 4w..4w+3; lane -> 4 channels (f32x4).
// ---------------------------------------------------------------------------
__global__ __launch_bounds__(256) void mixer_kernel(
    const float* __restrict__ x, const float* __restrict__ cw,
    const float* __restrict__ cb, const int* __restrict__ inv,
    const float* __restrict__ zrow, float* __restrict__ out) {
  __shared__ int s_inv[HS][HS];

  const int id = blockIdx.x;               // 1024 blocks
  const int rem = id >> 3;
  const int b = ((id & 7) << 1) + (rem >> 6);   // XCD-swizzled batch
  const int tile = rem & 63;
  const int gy0 = (tile >> 3) * TS;
  const int gx0 = (tile & 7) * TS;

  const int tid = threadIdx.x;
  const int lane = tid & 63;
  const int wv = tid >> 6;
  const int c4 = lane << 2;                // first channel of this lane

  for (int t = tid; t < HS * HS; t += 256) {
    const int wy = t / HS, wx = t - wy * HS;
    const int gy = gy0 - 1 + wy, gx = gx0 - 1 + wx;
    int nv = -1;
    if ((unsigned)gy < (unsigned)GW && (unsigned)gx < (unsigned)GW)
      nv = inv[(b << 14) + (gy << 7) + gx];
    s_inv[wy][wx] = nv;
  }

  // per-lane weights/bias for channels c4..c4+3
  f32x4 wq[9], bq;
#pragma unroll
  for (int cc = 0; cc < 4; ++cc) {
    bq[cc] = cb[c4 + cc];
#pragma unroll
    for (int j = 0; j < 9; ++j) wq[j][cc] = cw[(c4 + cc) * 9 + j];
  }
  __syncthreads();

  const float* __restrict__ xb = x + ((size_t)b << 22);
  float* __restrict__ ob = out + ((size_t)b << 22);
  const int r0 = wv << 2;                  // halo row base of this wave

  // sliding 3-column window + 1 prefetch column (all static after unroll)
  f32x4 cA[6], cB[6], cC[6], cD[6];
  LCOL(0, cA)
  LCOL(1, cB)
  LCOL(2, cC)
#pragma unroll
  for (int j = 2; j < HS; ++j) {
    // A) prefetch next column's 6 rows (independent of this column's compute)
    if (j + 1 < HS) { LCOL(j + 1, cD) }

    // B) compute outputs: tile rows r0..r0+3, tile column j-2 (halo col j-1)
#pragma unroll
    for (int rr = 0; rr < 4; ++rr) {
      f32x4 a = bq;
      a += wq[0] * cA[rr];
      a += wq[1] * cB[rr];
      a += wq[2] * cC[rr];
      a += wq[3] * cA[rr + 1];
      a += wq[4] * cB[rr + 1];
      a += wq[5] * cC[rr + 1];
      a += wq[6] * cA[rr + 2];
      a += wq[7] * cB[rr + 2];
      a += wq[8] * cC[rr + 2];
      f32x4 res;
#pragma unroll
      for (int cc = 0; cc < 4; ++cc)
        res[cc] = cB[rr + 1][cc] + gelu_fast(a[cc]);
      const int n = __builtin_amdgcn_readfirstlane(s_inv[r0 + rr + 1][j - 1]);
      __builtin_nontemporal_store(res, (f32x4*)(ob + ((size_t)n << 8) + c4));
    }
    // C) rotate window (SSA renames after full unroll)
#pragma unroll
    for (int r6 = 0; r6 < 6; ++r6) {
      cA[r6] = cB[r6];
      cB[r6] = cC[r6];
      cC[r6] = cD[r6];
    }
  }
}

// ---------------------------------------------------------------------------
extern "C" void kernel_launch(void* const* d_in, const int* in_sizes, int n_in,
                              void* d_out, int out_size, void* d_ws,
                              size_t ws_size, hipStream_t stream) {
  const float* x = (const float*)d_in[0];
  const int* coords = (const int*)d_in[1];
  const float* cw = (const float*)d_in[2];
  const float* cb = (const float*)d_in[3];
  float* out = (float*)d_out;
  int* inv = (int*)d_ws;                        // B*N ints = 1 MiB
  float* zrow = (float*)d_ws + (size_t)BB * NN; // 256 floats after inv

  {
    dim3 grid((BB * NN) / 256), block(256);
    build_inv_kernel<<<grid, block, 0, stream>>>(coords, inv, zrow);
  }
  {
    dim3 grid(BB * (GW / TS) * (GW / TS)), block(256);   // 1024 blocks
    mixer_kernel<<<grid, block, 0, stream>>>(x, cw, cb, inv, zrow, out);
  }
}

// Round 14
// 104.081 us; speedup vs baseline: 1.0670x; 1.0670x over previous
//
#include <hip/hip_runtime.h>
#include <hip/hip_bf16.h>

// Problem constants: B=16, N=16384, D=256, grid 128x128, K=3 depthwise, GELU.
// coords = per-batch permutation of all cells -> collision-free, min=(0,0).
//
// R14 = R13 + sched_barrier(0) pinning the column prefetch. R13 evidence:
// VGPR 92 (< 136 needed for a live prefetch column) and dur == R12 => the
// scheduler sank the prefetched loads back to their use. sched_barrier(0)
// forbids motion across it: the 6 loads of column j+1 (and their s_inv
// ds_read/readfirstlane chain) must issue BEFORE column j's ~520-cycle
// compute, so their waitcnt lands one full compute phase later.
#define BB 16
#define NN 16384
#define GW 128
#define TS 16
#define HS 18

typedef float f32x4 __attribute__((ext_vector_type(4)));

// ---------------------------------------------------------------------------
// Kernel 1: inverse permutation + zero-row init
// ---------------------------------------------------------------------------
__global__ __launch_bounds__(256) void build_inv_kernel(
    const int* __restrict__ coords, int* __restrict__ inv,
    float* __restrict__ zrow) {
  int i = blockIdx.x * blockDim.x + threadIdx.x;   // 0 .. B*N-1
  int b = i >> 14;
  int gx = coords[2 * (size_t)i];
  int gy = coords[2 * (size_t)i + 1];
  inv[(b << 14) + (gy << 7) + gx] = i & (NN - 1);
  if (blockIdx.x == 0) zrow[threadIdx.x] = 0.0f;   // 256 floats = 1 row
}

__device__ __forceinline__ float gelu_fast(float a) {
  // gelu_tanh(a) = a * sigmoid(1.5957691216*(a + 0.044715*a^3))
  // folded: sig = 1/(1+2^(-2.3022083*t))
  const float s = a * a;
  const float t = fmaf(0.044715f * a, s, a);
  const float e = __builtin_amdgcn_exp2f(t * -2.3022083f);
  return a * __builtin_amdgcn_rcpf(1.0f + e);
}

// load halo column j (6 stacked rows r0..r0+5) for this lane's 4 channels
#define LCOL(j, col)                                                      \
  _Pragma("unroll") for (int r6 = 0; r6 < 6; ++r6) {                      \
    const int n_ = __builtin_amdgcn_readfirstlane(s_inv[r0 + r6][j]);     \
    const float* p_ = (n_ >= 0) ? xb + ((size_t)n_ << 8) : zrow;          \
    col[r6] = *(const f32x4*)(p_ + c4);                                   \
  }

// ---------------------------------------------------------------------------
// Kernel 2: 16x16 tile; wave w -> rows 4w..4w+3; lane -> 4 channels (f32x4).
// ---------------------------------------------------------------------------
__global__ __launch_bounds__(256) void mixer_kernel(
    const float* __restrict__ x, const float* __restrict__ cw,
    const float* __restrict__ cb, const int* __restrict__ inv,
    const float* __restrict__ zrow, float* __restrict__ out) {
  __shared__ int s_inv[HS][HS];

  const int id = blockIdx.x;               // 1024 blocks
  const int rem = id >> 3;
  const int b = ((id & 7) << 1) + (rem >> 6);   // XCD-swizzled batch
  const int tile = rem & 63;
  const int gy0 = (tile >> 3) * TS;
  const int gx0 = (tile & 7) * TS;

  const int tid = threadIdx.x;
  const int lane = tid & 63;
  const int wv = tid >> 6;
  const int c4 = lane << 2;                // first channel of this lane

  for (int t = tid; t < HS * HS; t += 256) {
    const int wy = t / HS, wx = t - wy * HS;
    const int gy = gy0 - 1 + wy, gx = gx0 - 1 + wx;
    int nv = -1;
    if ((unsigned)gy < (unsigned)GW && (unsigned)gx < (unsigned)GW)
      nv = inv[(b << 14) + (gy << 7) + gx];
    s_inv[wy][wx] = nv;
  }

  // per-lane weights/bias for channels c4..c4+3
  f32x4 wq[9], bq;
#pragma unroll
  for (int cc = 0; cc < 4; ++cc) {
    bq[cc] = cb[c4 + cc];
#pragma unroll
    for (int j = 0; j < 9; ++j) wq[j][cc] = cw[(c4 + cc) * 9 + j];
  }
  __syncthreads();

  const float* __restrict__ xb = x + ((size_t)b << 22);
  float* __restrict__ ob = out + ((size_t)b << 22);
  const int r0 = wv << 2;                  // halo row base of this wave

  // sliding 3-column window + 1 prefetch column (all static after unroll)
  f32x4 cA[6], cB[6], cC[6], cD[6];
  LCOL(0, cA)
  LCOL(1, cB)
  LCOL(2, cC)
#pragma unroll
  for (int j = 2; j < HS; ++j) {
    // A) prefetch next column's 6 rows -- MUST issue before compute
    if (j + 1 < HS) { LCOL(j + 1, cD) }
    __builtin_amdgcn_sched_barrier(0);   // nothing crosses: loads stay issued

    // B) compute outputs: tile rows r0..r0+3, tile column j-2 (halo col j-1)
#pragma unroll
    for (int rr = 0; rr < 4; ++rr) {
      f32x4 a = bq;
      a += wq[0] * cA[rr];
      a += wq[1] * cB[rr];
      a += wq[2] * cC[rr];
      a += wq[3] * cA[rr + 1];
      a += wq[4] * cB[rr + 1];
      a += wq[5] * cC[rr + 1];
      a += wq[6] * cA[rr + 2];
      a += wq[7] * cB[rr + 2];
      a += wq[8] * cC[rr + 2];
      f32x4 res;
#pragma unroll
      for (int cc = 0; cc < 4; ++cc)
        res[cc] = cB[rr + 1][cc] + gelu_fast(a[cc]);
      const int n = __builtin_amdgcn_readfirstlane(s_inv[r0 + rr + 1][j - 1]);
      __builtin_nontemporal_store(res, (f32x4*)(ob + ((size_t)n << 8) + c4));
    }
    // C) rotate window (SSA renames after full unroll)
#pragma unroll
    for (int r6 = 0; r6 < 6; ++r6) {
      cA[r6] = cB[r6];
      cB[r6] = cC[r6];
      cC[r6] = cD[r6];
    }
  }
}

// ---------------------------------------------------------------------------
extern "C" void kernel_launch(void* const* d_in, const int* in_sizes, int n_in,
                              void* d_out, int out_size, void* d_ws,
                              size_t ws_size, hipStream_t stream) {
  const float* x = (const float*)d_in[0];
  const int* coords = (const int*)d_in[1];
  const float* cw = (const float*)d_in[2];
  const float* cb = (const float*)d_in[3];
  float* out = (float*)d_out;
  int* inv = (int*)d_ws;                        // B*N ints = 1 MiB
  float* zrow = (float*)d_ws + (size_t)BB * NN; // 256 floats after inv

  {
    dim3 grid((BB * NN) / 256), block(256);
    build_inv_kernel<<<grid, block, 0, stream>>>(coords, inv, zrow);
  }
  {
    dim3 grid(BB * (GW / TS) * (GW / TS)), block(256);   // 1024 blocks
    mixer_kernel<<<grid, block, 0, stream>>>(x, cw, cb, inv, zrow, out);
  }
}